// Round 8
// baseline (469.277 us; speedup 1.0000x reference)
//
#include <hip/hip_runtime.h>

// RWKV TimeMix: x->(shift,mix)->fused K/V/R GEMM (bf16 MFMA)->WKV windowed scan->O GEMM.
// GEMM: 256x256 tile, 8 waves (2x4), K processed as 32 half-tiles of BK=32.
// 4 LDS buffers (4x32KB); stage half-tile h+3 while computing h (A-half ph1, B-half ph2);
// ONE counted s_waitcnt vmcnt(8) per half-tile (never 0 in main loop) + barrier validates h+1.
// m201 phase template: {ds_reads; stage; s_barrier; lgkmcnt(0); sched_barrier; setprio; 16 MFMA; setprio; s_barrier}.
// LDS swizzle: k-slot s stored at slot s^((row>>1)&3) (R4-verified, 0 conflicts), source-side pre-swizzled.

#define DEV __device__ __forceinline__

constexpr int Bc = 32, Tc = 1024, Cc = 1024;
constexpr int Mdim = Bc * Tc;            // 32768
constexpr int Ndim = Cc;                 // 1024
constexpr int Kdim = Cc;                 // 1024
constexpr int NH = Kdim / 32;            // 32 half-tiles
constexpr int CHUNK = 128;               // scan output chunk
constexpr int LOOKB = 128;               // scan lookback (decay^128 <= 7.9e-5)
constexpr int NCH = Tc / CHUNK;          // 8

typedef short bf16x8 __attribute__((ext_vector_type(8)));
typedef float f32x4  __attribute__((ext_vector_type(4)));

DEV unsigned short f2bf(float f) {               // round-to-nearest-even f32->bf16
    unsigned u = __float_as_uint(f);
    u += 0x7FFFu + ((u >> 16) & 1u);
    return (unsigned short)(u >> 16);
}
DEV float bf2f(unsigned short s) { return __uint_as_float(((unsigned)s) << 16); }

// async global->LDS, 16B per lane; LDS dest = wave-uniform base + lane*16 (m104 semantics)
DEV void gload16(const unsigned short* g, const unsigned short* l) {
    __builtin_amdgcn_global_load_lds(
        (const __attribute__((address_space(1))) void*)g,
        (__attribute__((address_space(3))) void*)l, 16, 0, 0);
}

// ---------------- weight f32 -> bf16 ----------------
__global__ void wconv_kernel(const float* __restrict__ src, unsigned short* __restrict__ dst) {
    int i = blockIdx.x * blockDim.x + threadIdx.x;
    float4 v = ((const float4*)src)[i];
    ((ushort4*)dst)[i] = make_ushort4(f2bf(v.x), f2bf(v.y), f2bf(v.z), f2bf(v.w));
}

// ---------------- time shift + mix -> xm (bf16) ----------------
__global__ void xm_kernel(const float* __restrict__ x, const float* __restrict__ tm,
                          unsigned short* __restrict__ xm) {
    int i4 = blockIdx.x * blockDim.x + threadIdx.x;   // index in float4 units
    int c4 = i4 & (Cc / 4 - 1);                       // channel/4
    int t  = (i4 >> 8) & (Tc - 1);
    float4 xc = ((const float4*)x)[i4];
    float4 xp = make_float4(0.f, 0.f, 0.f, 0.f);
    if (t > 0) xp = ((const float4*)x)[i4 - Cc / 4];
    float4 tv = ((const float4*)tm)[c4];
    ushort4 o = make_ushort4(
        f2bf(xc.x * tv.x + xp.x * (1.f - tv.x)),
        f2bf(xc.y * tv.y + xp.y * (1.f - tv.y)),
        f2bf(xc.z * tv.z + xp.z * (1.f - tv.z)),
        f2bf(xc.w * tv.w + xp.w * (1.f - tv.w)));
    ((ushort4*)xm)[i4] = o;
}

// ---------------- 256x256-tile GEMM, C[m,nf] = sum_k A[m,k]*W[nf,k] ----------------
// FUSED=1: W has 3072 rows (Wk|Wv|Wr); blockIdx.y in [0,12); mode=y>>2 selects epilogue/output.
// FUSED=0: W has 1024 rows (Wo); blockIdx.y in [0,4); raw f32 output.
template <int FUSED>
__global__ __launch_bounds__(512, 2) void gemm256_kernel(
    const unsigned short* __restrict__ A,
    const unsigned short* __restrict__ W,
    unsigned short* __restrict__ ok,
    unsigned short* __restrict__ ov,
    unsigned short* __restrict__ orr,
    float* __restrict__ of)
{
    // 4 buffers x (A 256x32 + B 256x32) bf16 = 4 x 32KB = 128KB
    __shared__ unsigned short lds[65536];

    const int tid = threadIdx.x;
    const int l = tid & 63, w = tid >> 6;      // wave 0..7
    const int wr = w >> 2, wc = w & 3;         // 2M x 4N wave grid; per-wave out 128x64
    const int l15 = l & 15, l4 = l >> 4;
    const size_t row0 = (size_t)blockIdx.x * 256;
    const int ncol0 = blockIdx.y * 256;        // row offset into (fused) weight

    // staging: instr g covers rows [g*128, g*128+128): thread t -> row g*128+(t>>2), k-slot t&3
    const int rs = tid >> 2;
    const int cs = ((tid & 3) ^ ((tid >> 3) & 3)) << 3;   // pre-swizzled source k-col (elements)
    // frag read: row (..16m + l15), k-slot l4 stored at slot l4 ^ ((l15>>1)&3)
    const int csw = (l4 ^ ((l15 >> 1) & 3)) << 3;

    f32x4 acc[8][4];
#pragma unroll
    for (int m = 0; m < 8; m++)
#pragma unroll
        for (int n = 0; n < 4; n++)
#pragma unroll
            for (int q = 0; q < 4; q++) acc[m][n][q] = 0.f;

    // 2 gloads staging one 256x32 half (A: half_off=0 from A/row0; B: half_off=8192 from W/ncol0)
#define STAGE_AH(hh) {                                                                  \
    _Pragma("unroll")                                                                   \
    for (int g = 0; g < 2; g++)                                                         \
        gload16(A + (row0 + g * 128 + rs) * (size_t)Kdim + (hh) * 32 + cs,              \
                lds + ((hh) & 3) * 16384 + g * 4096 + w * 512); }
#define STAGE_BH(hh) {                                                                  \
    _Pragma("unroll")                                                                   \
    for (int g = 0; g < 2; g++)                                                         \
        gload16(W + (size_t)(ncol0 + g * 128 + rs) * Kdim + (hh) * 32 + cs,             \
                lds + ((hh) & 3) * 16384 + 8192 + g * 4096 + w * 512); }

    // prologue: stage half-tiles 0,1,2 (12 loads); retire h0's 4 -> vmcnt(8); validate
    STAGE_AH(0) STAGE_BH(0) STAGE_AH(1) STAGE_BH(1) STAGE_AH(2) STAGE_BH(2)
    asm volatile("s_waitcnt vmcnt(8)" ::: "memory");
    asm volatile("s_barrier" ::: "memory");

    for (int h = 0; h < NH; h++) {
        const unsigned short* Ab = lds + (h & 3) * 16384;
        const unsigned short* Bb = Ab + 8192;
        bf16x8 af[4], bfr[4];

        // ---- phase 1: read A-half0 (4) + B (4); stage A-half of h+3; MFMA acc[0..3][*] ----
#pragma unroll
        for (int mi = 0; mi < 4; mi++)
            af[mi] = *(const bf16x8*)(Ab + (wr * 128 + mi * 16 + l15) * 32 + csw);
#pragma unroll
        for (int n = 0; n < 4; n++)
            bfr[n] = *(const bf16x8*)(Bb + (wc * 64 + n * 16 + l15) * 32 + csw);
        if (h + 3 < NH) STAGE_AH(h + 3)
        asm volatile("s_barrier" ::: "memory");
        asm volatile("s_waitcnt lgkmcnt(0)" ::: "memory");
        __builtin_amdgcn_sched_barrier(0);
        __builtin_amdgcn_s_setprio(1);
#pragma unroll
        for (int mi = 0; mi < 4; mi++)
#pragma unroll
            for (int n = 0; n < 4; n++)
                acc[mi][n] = __builtin_amdgcn_mfma_f32_16x16x32_bf16(af[mi], bfr[n], acc[mi][n], 0, 0, 0);
        __builtin_amdgcn_s_setprio(0);
        asm volatile("s_barrier" ::: "memory");

        // ---- phase 2: read A-half1 (4); stage B-half of h+3; counted vmcnt; MFMA acc[4..7][*] ----
#pragma unroll
        for (int mi = 0; mi < 4; mi++)
            af[mi] = *(const bf16x8*)(Ab + (wr * 128 + (4 + mi) * 16 + l15) * 32 + csw);
        if (h + 3 < NH) STAGE_BH(h + 3)
        if (h < NH - 3) { asm volatile("s_waitcnt vmcnt(8)" ::: "memory"); }   // h+1 resident; h+2,h+3 in flight
        else           { asm volatile("s_waitcnt vmcnt(0)" ::: "memory"); }   // tail drain
        asm volatile("s_barrier" ::: "memory");
        asm volatile("s_waitcnt lgkmcnt(0)" ::: "memory");
        __builtin_amdgcn_sched_barrier(0);
        __builtin_amdgcn_s_setprio(1);
#pragma unroll
        for (int mi = 0; mi < 4; mi++)
#pragma unroll
            for (int n = 0; n < 4; n++)
                acc[4 + mi][n] = __builtin_amdgcn_mfma_f32_16x16x32_bf16(af[mi], bfr[n], acc[4 + mi][n], 0, 0, 0);
        __builtin_amdgcn_s_setprio(0);
        asm volatile("s_barrier" ::: "memory");
    }
#undef STAGE_AH
#undef STAGE_BH

    const int mode = FUSED ? (blockIdx.y >> 2) : 3;
    const int colb = FUSED ? ((blockIdx.y & 3) * 256) : ncol0;
#pragma unroll
    for (int m = 0; m < 8; m++)
#pragma unroll
        for (int n = 0; n < 4; n++)
#pragma unroll
            for (int q = 0; q < 4; q++) {
                size_t row = row0 + wr * 128 + m * 16 + l4 * 4 + q;
                int col = colb + wc * 64 + n * 16 + l15;
                size_t idx = row * Ndim + col;
                float v = acc[m][n][q];
                if (FUSED) {
                    if (mode == 0)      ok[idx]  = f2bf(__expf(fminf(v, 60.f)));
                    else if (mode == 1) ov[idx]  = f2bf(v);
                    else                orr[idx] = f2bf(1.f / (1.f + __expf(-v)));
                } else {
                    of[idx] = v;
                }
            }
}

// ---------------- windowed WKV scan + sig(r)*(wkv/wk) -> rwkv bf16 ----------------
// thread <-> (b, chunk, c). Scans [t0-LOOKB, t0+CHUNK), outputs only in [t0, t0+CHUNK).
// kv = kexp*v computed inline. sr[] already = sigmoid(r).
__global__ __launch_bounds__(256) void scan_kernel(
    const unsigned short* __restrict__ kexp, const unsigned short* __restrict__ vb,
    const unsigned short* __restrict__ sr,
    const float* __restrict__ td, const float* __restrict__ tf,
    unsigned short* __restrict__ rwkv)
{
    int c = blockIdx.x * blockDim.x + threadIdx.x;
    int ch = blockIdx.y;
    int b  = blockIdx.z;
    int t0 = ch * CHUNK;
    int tstart = t0 - LOOKB; if (tstart < 0) tstart = 0;

    float decay = __expf(-__expf(td[c]));
    float fw = __expf(tf[c]);
    float Skv = 0.f, Sk = 0.f;

    size_t base = (size_t)b * Tc * Cc + c;
    size_t idx = base + (size_t)tstart * Cc;
#pragma unroll 8
    for (int t = tstart; t < t0; t++, idx += Cc) {
        float kk = bf2f(kexp[idx]);
        float y  = kk * bf2f(vb[idx]);
        Skv = decay * Skv + y;
        Sk  = decay * Sk  + kk;
    }
#pragma unroll 8
    for (int t = t0; t < t0 + CHUNK; t++, idx += Cc) {
        float kk = bf2f(kexp[idx]);
        float y  = kk * bf2f(vb[idx]);
        float wkv = fw * y + Skv;            // eps = 0
        float wk  = 1e-16f + fw * kk + Sk;   // eps = 1e-16
        float sig = bf2f(sr[idx]);
        rwkv[idx] = f2bf(sig * (wkv / wk));
        Skv = decay * Skv + y;
        Sk  = decay * Sk  + kk;
    }
}

extern "C" void kernel_launch(void* const* d_in, const int* in_sizes, int n_in,
                              void* d_out, int out_size, void* d_ws, size_t ws_size,
                              hipStream_t stream) {
    const float* x  = (const float*)d_in[0];
    const float* td = (const float*)d_in[1];
    const float* tf = (const float*)d_in[2];
    const float* tm = (const float*)d_in[3];
    const float* Wk = (const float*)d_in[4];
    const float* Wv = (const float*)d_in[5];
    const float* Wr = (const float*)d_in[6];
    const float* Wo = (const float*)d_in[7];

    const size_t BTC = (size_t)Bc * Tc * Cc;   // 33,554,432
    const size_t WN  = (size_t)Cc * Cc;        // 1,048,576

    char* ws = (char*)d_ws;
    unsigned short* wkb   = (unsigned short*)ws; ws += WN * 2;   // fused W base: Wk|Wv|Wr contiguous
    unsigned short* wvb   = (unsigned short*)ws; ws += WN * 2;
    unsigned short* wrb   = (unsigned short*)ws; ws += WN * 2;
    unsigned short* wob   = (unsigned short*)ws; ws += WN * 2;
    unsigned short* xm    = (unsigned short*)ws; ws += BTC * 2;  // reused as rwkv
    unsigned short* kexpb = (unsigned short*)ws; ws += BTC * 2;
    unsigned short* vbb   = (unsigned short*)ws; ws += BTC * 2;
    unsigned short* srb   = (unsigned short*)ws; ws += BTC * 2;
    float* outp = (float*)d_out;

    // 1) weights -> bf16
    wconv_kernel<<<WN / 1024, 256, 0, stream>>>(Wk, wkb);
    wconv_kernel<<<WN / 1024, 256, 0, stream>>>(Wv, wvb);
    wconv_kernel<<<WN / 1024, 256, 0, stream>>>(Wr, wrb);
    wconv_kernel<<<WN / 1024, 256, 0, stream>>>(Wo, wob);

    // 2) time shift + mix
    xm_kernel<<<BTC / 4 / 256, 256, 0, stream>>>(x, tm, xm);

    // 3) fused K/V/R GEMM (N=3072 over contiguous Wk|Wv|Wr)
    gemm256_kernel<1><<<dim3(Mdim / 256, 12), 512, 0, stream>>>(
        xm, wkb, kexpb, vbb, srb, nullptr);

    // 4) windowed WKV scan (writes rwkv over xm)
    scan_kernel<<<dim3(Cc / 256, NCH, Bc), 256, 0, stream>>>(kexpb, vbb, srb, td, tf, xm);

    // 5) output GEMM -> d_out (f32)
    gemm256_kernel<0><<<dim3(Mdim / 256, 4), 512, 0, stream>>>(
        xm, wob, nullptr, nullptr, nullptr, outp);
}